// Round 1
// baseline (29148.492 us; speedup 1.0000x reference)
//
#include <hip/hip_runtime.h>
#include <math.h>

// Problem constants
#define BB  64
#define TT  512
#define IN  64
#define HH  512
#define ZHH 128
#define NZZ 32
#define NWG 256
#define NT  256

// workspace float offsets
#define O_H      0
#define O_HHATA  (O_H + BB*HH)          // 32768
#define O_HHATB  (O_HHATA + BB*ZHH)     // 40960
#define O_WHH    (O_HHATB + BB*ZHH)     // 49152
#define O_WXX    (O_WHH + BB*3*HH)      // 147456
#define O_Z      (O_WXX + BB*3*HH)      // 245760
#define O_BAR    (O_Z + BB*288)         // 264192  (ints; gen at +32)

__device__ __forceinline__ float sigmoidf_(float x) {
    return 1.0f / (1.0f + __expf(-x));
}

// Device-wide barrier: counter + generation, agent scope.
// __threadfence() before arrival (release: L2 writeback) and after exit
// (acquire: invalidate) gives cross-XCD visibility of normal stores.
__device__ __forceinline__ void gbar(int* bar, int* gen) {
    __syncthreads();
    if (threadIdx.x == 0) {
        __threadfence();
        int g = __hip_atomic_load(gen, __ATOMIC_RELAXED, __HIP_MEMORY_SCOPE_AGENT);
        int prev = __hip_atomic_fetch_add(bar, 1, __ATOMIC_RELAXED, __HIP_MEMORY_SCOPE_AGENT);
        if (prev == NWG - 1) {
            __hip_atomic_store(bar, 0, __ATOMIC_RELAXED, __HIP_MEMORY_SCOPE_AGENT);
            __hip_atomic_store(gen, g + 1, __ATOMIC_RELEASE, __HIP_MEMORY_SCOPE_AGENT);
        } else {
            while (__hip_atomic_load(gen, __ATOMIC_RELAXED, __HIP_MEMORY_SCOPE_AGENT) == g) {
                __builtin_amdgcn_s_sleep(2);
            }
        }
        __threadfence();
    }
    __syncthreads();
}

__device__ __forceinline__ float dot4(const float4 a, const float4 b) {
    return a.x*b.x + a.y*b.y + a.z*b.z + a.w*b.w;
}

__global__ __launch_bounds__(NT)
void hypercell_persistent(
    const float* __restrict__ xs, const float* __restrict__ cond,
    const float* __restrict__ h_c, const float* __restrict__ h_c_hat,
    const float* __restrict__ x2h_w, const float* __restrict__ x2h_b,
    const float* __restrict__ h2h_w, const float* __restrict__ h2h_b,
    const float* __restrict__ zh_w, const float* __restrict__ zh_b,
    const float* __restrict__ zx_w, const float* __restrict__ zx_b,
    const float* __restrict__ zb_w,
    const float* __restrict__ dh_w, const float* __restrict__ dx_w,
    const float* __restrict__ db_w, const float* __restrict__ db_b,
    const float* __restrict__ wh, const float* __restrict__ wx,
    float* __restrict__ out, float* __restrict__ ws)
{
    // 61.4 KB static LDS, manually partitioned per phase
    __shared__ float sm[15360];

    const int tid = threadIdx.x;
    const int wg  = blockIdx.x;
    const int bg  = wg >> 5;     // 0..7  : batch group (8 batches)
    const int sub = wg & 31;     // 0..31 : row/j/R/h group depending on phase
    const int b0  = bg * 8;

    int* bar = (int*)(ws + O_BAR);
    int* gen = bar + 32;         // separate 128B line

    // ---- init: copy initial states into ws ----
    for (int i = wg * NT + tid; i < BB * HH; i += NWG * NT) ws[O_H + i] = h_c[i];
    for (int i = wg * NT + tid; i < BB * ZHH; i += NWG * NT) ws[O_HHATA + i] = h_c_hat[i];
    gbar(bar, gen);

    const int row0 = sub * 48;   // whh/wxx rows for this WG (of 1536)
    const int j0   = sub * 4;    // hyper j-slice
    const int R0   = sub * 9;    // z rows
    const int hs0  = sub * 16;   // phase-C h tile

    for (int t = 0; t < TT; ++t) {
        const int hcur = (t & 1) ? O_HHATB : O_HHATA;
        const int hnxt = (t & 1) ? O_HHATA : O_HHATB;

        // ================= PHASE A1: whh + wxx =================
        // sm: h_s[8][516] @0, x_s[8][68] @4128, wx_s[48][68] @4672, w_s[48][132] @7936
        float* h_s  = sm;
        float* x_s  = sm + 4128;
        float* wx_s = sm + 4672;
        float* w_s  = sm + 7936;

        for (int i = tid; i < 1024; i += NT) {   // 8*512 floats as float4
            int b = i >> 7, kq = i & 127;
            *(float4*)&h_s[b*516 + kq*4] =
                *(const float4*)&ws[O_H + (size_t)(b0+b)*HH + kq*4];
        }
        for (int i = tid; i < 128; i += NT) {    // 8*64 floats as float4
            int b = i >> 4, kq = i & 15;
            *(float4*)&x_s[b*68 + kq*4] =
                *(const float4*)&xs[((size_t)(b0+b)*TT + t)*IN + kq*4];
        }
        for (int i = tid; i < 768; i += NT) {    // 48*64 floats as float4
            int r = i >> 4, kq = i & 15;
            *(float4*)&wx_s[r*68 + kq*4] =
                *(const float4*)&wx[(size_t)(row0+r)*IN + kq*4];
        }
        __syncthreads();

        // wxx: 384 dots (48 rows x 8 b), K=64
        for (int d = tid; d < 384; d += NT) {
            int r = d >> 3, b = d & 7;
            const float4* xv = (const float4*)&x_s[b*68];
            const float4* wv = (const float4*)&wx_s[r*68];
            float acc = 0.f;
            #pragma unroll
            for (int k4 = 0; k4 < 16; ++k4) acc += dot4(xv[k4], wv[k4]);
            ws[O_WXX + (size_t)(b0+b)*1536 + row0 + r] = acc;
        }

        // whh: 384 dots K=512, K-tiled by 128, 2 rows/thread (shared h)
        {
            const int rA = tid >> 3, b = tid & 7;
            const int rB = rA + 32;
            const int rBs = (rB < 48) ? rB : 0;   // clamp to stay in-bounds
            float accA = 0.f, accB = 0.f;
            for (int kt = 0; kt < 4; ++kt) {
                __syncthreads();
                for (int i = tid; i < 1536; i += NT) {  // 48*128 floats as float4
                    int r = i >> 5, kq = i & 31;
                    *(float4*)&w_s[r*132 + kq*4] =
                        *(const float4*)&wh[(size_t)(row0+r)*HH + kt*128 + kq*4];
                }
                __syncthreads();
                const float4* hv4 = (const float4*)&h_s[b*516 + kt*128];
                const float4* wa4 = (const float4*)&w_s[rA*132];
                const float4* wb4 = (const float4*)&w_s[rBs*132];
                #pragma unroll 8
                for (int k4 = 0; k4 < 32; ++k4) {
                    float4 hv = hv4[k4];
                    accA += dot4(hv, wa4[k4]);
                    accB += dot4(hv, wb4[k4]);
                }
            }
            ws[O_WHH + (size_t)(b0+b)*1536 + row0 + rA] = accA;
            if (rB < 48)
                ws[O_WHH + (size_t)(b0+b)*1536 + row0 + rB] = accB;
        }
        __syncthreads();

        // ================= PHASE A2: hyper GRU -> hhat_new =================
        // sm: h_s kept @0, cond_s[8][68] @4128, hh_s[8][132] @4672,
        //     xw_s[12][580] @5728, hw_s[12][132] @12688, pre_s[192] @14272
        float* cond_s = sm + 4128;
        float* hh_s   = sm + 4672;
        float* xw_s   = sm + 5728;
        float* hw_s   = sm + 12688;
        float* pre_s  = sm + 14272;

        for (int i = tid; i < 128; i += NT) {
            int b = i >> 4, kq = i & 15;
            *(float4*)&cond_s[b*68 + kq*4] =
                *(const float4*)&cond[(size_t)(b0+b)*IN + kq*4];
        }
        for (int i = tid; i < 256; i += NT) {    // 8*128 as float4
            int b = i >> 5, kq = i & 31;
            *(float4*)&hh_s[b*132 + kq*4] =
                *(const float4*)&ws[hcur + (size_t)(b0+b)*ZHH + kq*4];
        }
        for (int i = tid; i < 1728; i += NT) {   // 12*576 as float4
            int rr = i / 144, kq = i % 144;
            int grow = (rr >> 2)*128 + j0 + (rr & 3);
            *(float4*)&xw_s[rr*580 + kq*4] =
                *(const float4*)&x2h_w[(size_t)grow*576 + kq*4];
        }
        for (int i = tid; i < 384; i += NT) {    // 12*128 as float4
            int rr = i >> 5, kq = i & 31;
            int grow = (rr >> 2)*128 + j0 + (rr & 3);
            *(float4*)&hw_s[rr*132 + kq*4] =
                *(const float4*)&h2h_w[(size_t)grow*128 + kq*4];
        }
        __syncthreads();

        if (tid < 96) {             // ih dots: K = 512 (h) + 64 (cond)
            int b = tid / 12, rr = tid % 12;
            int grow = (rr >> 2)*128 + j0 + (rr & 3);
            float acc = x2h_b[grow];
            const float4* hv = (const float4*)&h_s[b*516];
            const float4* wv = (const float4*)&xw_s[rr*580];
            #pragma unroll 8
            for (int k4 = 0; k4 < 128; ++k4) acc += dot4(hv[k4], wv[k4]);
            const float4* cv = (const float4*)&cond_s[b*68];
            const float4* wc = (const float4*)&xw_s[rr*580 + 512];
            #pragma unroll
            for (int k4 = 0; k4 < 16; ++k4) acc += dot4(cv[k4], wc[k4]);
            pre_s[b*12 + rr] = acc;
        } else if (tid < 192) {     // hh dots: K = 128
            int q = tid - 96; int b = q / 12, rr = q % 12;
            int grow = (rr >> 2)*128 + j0 + (rr & 3);
            float acc = h2h_b[grow];
            const float4* hv = (const float4*)&hh_s[b*132];
            const float4* wv = (const float4*)&hw_s[rr*132];
            #pragma unroll 8
            for (int k4 = 0; k4 < 32; ++k4) acc += dot4(hv[k4], wv[k4]);
            pre_s[96 + b*12 + rr] = acc;
        }
        __syncthreads();

        if (tid < 32) {             // gate math -> hhat_new[b, j0+jj]
            int b = tid >> 2, jj = tid & 3, j = j0 + jj;
            float i_r = pre_s[b*12 + jj], i_i = pre_s[b*12 + 4 + jj], i_n = pre_s[b*12 + 8 + jj];
            float h_r = pre_s[96 + b*12 + jj], h_i = pre_s[96 + b*12 + 4 + jj], h_n = pre_s[96 + b*12 + 8 + jj];
            float r = sigmoidf_(i_r + h_r);
            float g = sigmoidf_(i_i + h_i);
            float n = tanhf(i_n + r * h_n);
            float hold = hh_s[b*132 + j];
            float hnew = n + g * (hold - n);
            ws[hnxt + (size_t)(b0+b)*ZHH + j] = hnew;
            if (t == TT - 1)
                out[(size_t)BB*TT*HH + (size_t)BB*HH + (size_t)(b0+b)*ZHH + j] = hnew;
        }
        gbar(bar, gen);

        // ================= PHASE B: z = hhat_new @ zw^T =================
        // sm: hn_s[8][132] @0, zw_s[9][132] @1056
        for (int i = tid; i < 256; i += NT) {
            int b = i >> 5, kq = i & 31;
            *(float4*)&sm[b*132 + kq*4] =
                *(const float4*)&ws[hnxt + (size_t)(b0+b)*ZHH + kq*4];
        }
        for (int i = tid; i < 288; i += NT) {    // 9*128 as float4
            int rr = i / 32, kq = i % 32;
            int R = R0 + rr; int kind = R / 96, r96 = R % 96;
            const float* wsrc = (kind == 0) ? zh_w : ((kind == 1) ? zx_w : zb_w);
            *(float4*)&sm[1056 + rr*132 + kq*4] =
                *(const float4*)&wsrc[(size_t)r96*ZHH + kq*4];
        }
        __syncthreads();
        if (tid < 72) {
            int b = tid / 9, rr = tid % 9;
            int R = R0 + rr; int kind = R / 96, r96 = R % 96;
            float acc = (kind == 0) ? zh_b[r96] : ((kind == 1) ? zx_b[r96] : 0.f);
            const float4* hv = (const float4*)&sm[b*132];
            const float4* wv = (const float4*)&sm[1056 + rr*132];
            #pragma unroll 8
            for (int k4 = 0; k4 < 32; ++k4) acc += dot4(hv[k4], wv[k4]);
            ws[O_Z + (size_t)(b0+b)*288 + R] = acc;
        }
        gbar(bar, gen);

        // ================= PHASE C: d scales + gates -> h_new =================
        // sm: z_s[8][292] @0, dw_s[9][16][36] @2336, dbb_s[48] @7520
        for (int i = tid; i < 576; i += NT) {    // 8*288 as float4
            int b = i / 72, rq = i % 72;
            *(float4*)&sm[b*292 + rq*4] =
                *(const float4*)&ws[O_Z + (size_t)(b0+b)*288 + rq*4];
        }
        for (int i = tid; i < 1152; i += NT) {   // 3*3*16*32 as float4
            int kind = i / 384, rem = i % 384, l = rem / 128, idx4 = rem % 128;
            int hh_i = idx4 >> 3, nz4 = idx4 & 7;
            const float* src = (kind == 0) ? dh_w : ((kind == 1) ? dx_w : db_w);
            *(float4*)&sm[2336 + ((kind*3 + l)*16 + hh_i)*36 + nz4*4] =
                *(const float4*)&src[(size_t)l*HH*NZZ + (size_t)(hs0+hh_i)*NZZ + nz4*4];
        }
        if (tid < 48) {
            int l = tid / 16, hh_i = tid % 16;
            sm[7520 + l*16 + hh_i] = db_b[l*HH + hs0 + hh_i];
        }
        __syncthreads();
        if (tid < 128) {
            int b = tid >> 4, hh_i = tid & 15;
            int h_idx = hs0 + hh_i;
            float dv[3][3];
            #pragma unroll
            for (int kind = 0; kind < 3; ++kind) {
                #pragma unroll
                for (int l = 0; l < 3; ++l) {
                    const float4* zp = (const float4*)&sm[b*292 + kind*96 + l*32];
                    const float4* wp = (const float4*)&sm[2336 + ((kind*3 + l)*16 + hh_i)*36];
                    float acc = 0.f;
                    #pragma unroll
                    for (int k4 = 0; k4 < 8; ++k4) acc += dot4(zp[k4], wp[k4]);
                    dv[kind][l] = acc;
                }
            }
            size_t wbase = (size_t)(b0+b)*1536 + h_idx;
            float whh0 = ws[O_WHH + wbase];
            float whh1 = ws[O_WHH + wbase + 512];
            float whh2 = ws[O_WHH + wbase + 1024];
            float wxx0 = ws[O_WXX + wbase];
            float wxx1 = ws[O_WXX + wbase + 512];
            float wxx2 = ws[O_WXX + wbase + 1024];
            float db0 = dv[2][0] + sm[7520 + hh_i];
            float db1 = dv[2][1] + sm[7520 + 16 + hh_i];
            float db2 = dv[2][2] + sm[7520 + 32 + hh_i];
            float r0 = sigmoidf_(dv[0][0]*whh0 + dv[1][0]*wxx0 + db0);
            float g0 = sigmoidf_(dv[0][1]*whh1 + dv[1][1]*wxx1 + db1);
            float n0 = tanhf(r0 * dv[0][2] * whh2 + dv[1][2]*wxx2 + db2);
            size_t hg = (size_t)(b0+b)*HH + h_idx;
            float hold = ws[O_H + hg];
            float hnew = n0 + g0 * (hold - n0);
            ws[O_H + hg] = hnew;
            out[((size_t)(b0+b)*TT + t)*HH + h_idx] = hnew;
            if (t == TT - 1) out[(size_t)BB*TT*HH + hg] = hnew;
        }
        gbar(bar, gen);
    }
}

extern "C" void kernel_launch(void* const* d_in, const int* in_sizes, int n_in,
                              void* d_out, int out_size, void* d_ws, size_t ws_size,
                              hipStream_t stream) {
    const float* xs      = (const float*)d_in[0];
    const float* cond    = (const float*)d_in[1];
    const float* h_c     = (const float*)d_in[2];
    const float* h_c_hat = (const float*)d_in[3];
    const float* x2h_w   = (const float*)d_in[4];
    const float* x2h_b   = (const float*)d_in[5];
    const float* h2h_w   = (const float*)d_in[6];
    const float* h2h_b   = (const float*)d_in[7];
    const float* zh_w    = (const float*)d_in[8];
    const float* zh_b    = (const float*)d_in[9];
    const float* zx_w    = (const float*)d_in[10];
    const float* zx_b    = (const float*)d_in[11];
    const float* zb_w    = (const float*)d_in[12];
    const float* dh_w    = (const float*)d_in[13];
    const float* dx_w    = (const float*)d_in[14];
    const float* db_w    = (const float*)d_in[15];
    const float* db_b    = (const float*)d_in[16];
    const float* wh      = (const float*)d_in[17];
    const float* wx      = (const float*)d_in[18];
    float* out = (float*)d_out;
    float* ws  = (float*)d_ws;

    // zero the barrier lines (ws is poisoned 0xAA before every launch)
    hipMemsetAsync((char*)d_ws + (size_t)O_BAR * 4, 0, 256, stream);

    hipLaunchKernelGGL(hypercell_persistent, dim3(NWG), dim3(NT), 0, stream,
                       xs, cond, h_c, h_c_hat, x2h_w, x2h_b, h2h_w, h2h_b,
                       zh_w, zh_b, zx_w, zx_b, zb_w, dh_w, dx_w, db_w, db_b,
                       wh, wx, out, ws);
}